// Round 3
// baseline (620.909 us; speedup 1.0000x reference)
//
#include <hip/hip_runtime.h>
#include <hip/hip_bf16.h>
#include <cstdint>
#include <cstddef>

#define B_ 8
#define T_ 4096
#define D_ 1024
#define H_ 1024
#define M_ (B_*T_)
#define NCHUNK 64
#define CLEN 64

using bf16x8   = __attribute__((ext_vector_type(8))) __bf16;
using floatx4  = __attribute__((ext_vector_type(4))) float;
using float4v  = __attribute__((ext_vector_type(4))) float;
using ushort4v = __attribute__((ext_vector_type(4))) unsigned short;
using aw2_t    = __attribute__((ext_vector_type(2))) _Float16;  // packed (a, w)
using halfx8   = __attribute__((ext_vector_type(8))) _Float16;  // 4 aw2 pairs

__device__ inline unsigned short f2bf(float f) {
  union { float f; unsigned u; } v; v.f = f;
  unsigned u = v.u;
  u += 0x7fffu + ((u >> 16) & 1u);   // round-to-nearest-even
  return (unsigned short)(u >> 16);
}

__device__ inline void async_load16(const void* g, void* l) {
  __builtin_amdgcn_global_load_lds((const __attribute__((address_space(1))) void*)g,
                                   (__attribute__((address_space(3))) void*)l,
                                   16, 0, 0);
}

// ---------------- cast x (fp32 -> bf16), 8 elems/thread ----------------
__global__ __launch_bounds__(256) void cast_x_kernel(const float* __restrict__ x,
                                                     unsigned short* __restrict__ xb) {
  size_t i = ((size_t)blockIdx.x * 256 + threadIdx.x) * 2;  // 2 groups of 4
#pragma unroll
  for (int j = 0; j < 2; ++j) {
    float4v v = ((const float4v*)x)[i + j];
    ushort4v o = { f2bf(v[0]), f2bf(v[1]), f2bf(v[2]), f2bf(v[3]) };
    ((ushort4v*)xb)[i + j] = o;
  }
}

// ------------- transpose + cast W [K][N] -> Wt [N][K] bf16 -------------
__global__ __launch_bounds__(256) void transpose_w_kernel(const float* __restrict__ Wz,
                                                          const float* __restrict__ Wh,
                                                          unsigned short* __restrict__ Wzt,
                                                          unsigned short* __restrict__ Wht) {
  __shared__ float tile[32][33];
  const float* W = blockIdx.z ? Wh : Wz;
  unsigned short* Wt = blockIdx.z ? Wht : Wzt;
  int n0 = blockIdx.x * 32, k0 = blockIdx.y * 32;
#pragma unroll
  for (int j = 0; j < 4; ++j) {
    int kr = threadIdx.y + j * 8;
    tile[kr][threadIdx.x] = W[(size_t)(k0 + kr) * H_ + n0 + threadIdx.x];
  }
  __syncthreads();
#pragma unroll
  for (int j = 0; j < 4; ++j) {
    int nr = threadIdx.y + j * 8;
    Wt[(size_t)(n0 + nr) * D_ + k0 + threadIdx.x] = f2bf(tile[threadIdx.x][nr]);
  }
}

// ------------- dual-output MFMA GEMM + activation epilogue -------------
// A staged in LDS via global_load_lds; B fragments loaded DIRECTLY from
// global (weights are 4 MB, L2-resident) -> halves ds_read traffic.
// XCD swizzle: all 16 n-blocks of one m-strip consecutive on one XCD.
// tile: 128 rows x 64 cols (dual output), BK=32, 4 waves (2x2), 256 thr
__global__ __launch_bounds__(256) void gemm_kernel(
    const unsigned short* __restrict__ xb,    // [M_][D_] bf16
    const unsigned short* __restrict__ wzt,   // [H_][D_] bf16 (transposed)
    const unsigned short* __restrict__ wht,   // [H_][D_] bf16
    const float* __restrict__ bz, const float* __restrict__ bh,
    aw2_t* __restrict__ aw_out) {
  __shared__ __align__(16) unsigned short ldsA[128 * 32];

  const int tid = threadIdx.x;
  const int lane = tid & 63, wid = tid >> 6;
  const int wm = wid >> 1, wn = wid & 1;
  const int row16 = lane & 15, quad = lane >> 4;

  // XCD-aware swizzle: g%8 tracks XCD; 16 n-blocks of an m-strip adjacent per XCD
  int g = blockIdx.x;
  int x = g & 7, j = g >> 3;
  int n_idx = j & 15;
  int m_idx = (x << 5) | (j >> 4);
  const int m0 = m_idx * 128, n0 = n_idx * 64;

  floatx4 accz[4][2], acch[4][2];
#pragma unroll
  for (int mi = 0; mi < 4; ++mi)
#pragma unroll
    for (int ni = 0; ni < 2; ++ni) {
      accz[mi][ni] = (floatx4){0.f, 0.f, 0.f, 0.f};
      acch[mi][ni] = (floatx4){0.f, 0.f, 0.f, 0.f};
    }

  // B fragment base pointers (per-lane), advance by 64B per k-step
  const char* bzp[2];
  const char* bhp[2];
#pragma unroll
  for (int ni = 0; ni < 2; ++ni) {
    int row = n0 + wn * 32 + ni * 16 + row16;
    bzp[ni] = (const char*)(wzt + (size_t)row * D_ + quad * 8);
    bhp[ni] = (const char*)(wht + (size_t)row * D_ + quad * 8);
  }
  const unsigned short* arow0 = xb + (size_t)(m0 + (tid >> 2)) * D_ + (tid & 3) * 8;
  const unsigned short* arow1 = xb + (size_t)(m0 + 64 + (tid >> 2)) * D_ + (tid & 3) * 8;

  for (int kk = 0; kk < D_; kk += 32) {
    // stage A tile (128x32 = 8KB, 2 x 16B per thread)
    async_load16(arow0 + kk, &ldsA[tid * 8]);
    async_load16(arow1 + kk, &ldsA[(tid + 256) * 8]);
    // B fragments straight from global (L2-hot)
    bf16x8 bzf[2], bhf[2];
#pragma unroll
    for (int ni = 0; ni < 2; ++ni) {
      bzf[ni] = *(const bf16x8*)(bzp[ni] + kk * 2);
      bhf[ni] = *(const bf16x8*)(bhp[ni] + kk * 2);
    }
    __syncthreads();   // drains vmcnt: A staged (B loads complete too)

    bf16x8 af[4];
#pragma unroll
    for (int mi = 0; mi < 4; ++mi)
      af[mi] = *(const bf16x8*)&ldsA[(wm * 64 + mi * 16 + row16) * 32 + quad * 8];
#pragma unroll
    for (int mi = 0; mi < 4; ++mi)
#pragma unroll
      for (int ni = 0; ni < 2; ++ni) {
        accz[mi][ni] = __builtin_amdgcn_mfma_f32_16x16x32_bf16(af[mi], bzf[ni], accz[mi][ni], 0, 0, 0);
        acch[mi][ni] = __builtin_amdgcn_mfma_f32_16x16x32_bf16(af[mi], bhf[ni], acch[mi][ni], 0, 0, 0);
      }
    __syncthreads();
  }

  // epilogue: C/D layout col=lane&15, row=quad*4+reg
#pragma unroll
  for (int mi = 0; mi < 4; ++mi) {
#pragma unroll
    for (int ni = 0; ni < 2; ++ni) {
      int col = n0 + wn * 32 + ni * 16 + row16;
      float bzv = bz[col], bhv = bh[col];
#pragma unroll
      for (int r = 0; r < 4; ++r) {
        int row = m0 + wm * 64 + mi * 16 + quad * 4 + r;
        float k   = accz[mi][ni][r] + bzv;
        float pre = acch[mi][ni][r] + bhv;
        float z  = 1.f / (1.f + __expf(-k));   // sigmoid(k)
        float av = 1.f / (1.f + __expf(k));    // sigmoid(-k) = 1-z
        float gg = (pre >= 0.f) ? (pre + 0.5f) : 1.f / (1.f + __expf(-pre));
        aw2_t o = { (_Float16)av, (_Float16)(z * gg) };
        aw_out[(size_t)row * H_ + col] = o;
      }
    }
  }
}

// ------------- scan pass 1: per-chunk (P = prod a, S = local scan), 4 h per thread -------------
// P,S layout: [b][h][c]  (contiguous in c for fast pass2)
__global__ __launch_bounds__(256) void scan_pass1(const halfx8* __restrict__ aw,
                                                  float* __restrict__ P, float* __restrict__ S) {
  int c = blockIdx.x;     // chunk
  int b = blockIdx.y;     // batch
  int h4 = threadIdx.x;   // h = h4*4
  size_t base = (size_t)(b * T_ + c * CLEN) * (H_ / 4) + h4;
  float p0 = 1.f, p1 = 1.f, p2 = 1.f, p3 = 1.f;
  float s0 = 0.f, s1 = 0.f, s2 = 0.f, s3 = 0.f;
#pragma unroll 8
  for (int i = 0; i < CLEN; ++i) {
    halfx8 v = aw[base + (size_t)i * (H_ / 4)];
    float a0 = (float)v[0], w0 = (float)v[1];
    float a1 = (float)v[2], w1 = (float)v[3];
    float a2 = (float)v[4], w2 = (float)v[5];
    float a3 = (float)v[6], w3 = (float)v[7];
    s0 = a0 * s0 + w0; p0 *= a0;
    s1 = a1 * s1 + w1; p1 *= a1;
    s2 = a2 * s2 + w2; p2 *= a2;
    s3 = a3 * s3 + w3; p3 *= a3;
  }
  size_t o = ((size_t)b * H_ + h4 * 4) * NCHUNK + c;
  P[o] = p0; P[o + NCHUNK] = p1; P[o + 2 * NCHUNK] = p2; P[o + 3 * NCHUNK] = p3;
  S[o] = s0; S[o + NCHUNK] = s1; S[o + 2 * NCHUNK] = s2; S[o + 3 * NCHUNK] = s3;
}

// ------------- scan pass 2: chunk-level carries + out[:,0,:] -------------
__global__ __launch_bounds__(256) void scan_pass2(const float* __restrict__ h0,
                                                  const float* __restrict__ P,
                                                  const float* __restrict__ S,
                                                  float* __restrict__ carry,
                                                  float* __restrict__ out) {
  int gid = blockIdx.x * 256 + threadIdx.x;  // 0..8191
  int b = gid >> 10, h = gid & 1023;
  float v = h0[(size_t)b * H_ + h];
  float cur = (v >= 0.f) ? (v + 0.5f) : 1.f / (1.f + __expf(-v));  // g(h0)
  out[((size_t)b * (T_ + 1)) * H_ + h] = cur;
  const float4v* Pv = (const float4v*)&P[((size_t)b * H_ + h) * NCHUNK];
  const float4v* Sv = (const float4v*)&S[((size_t)b * H_ + h) * NCHUNK];
  float4v* Cv = (float4v*)&carry[((size_t)b * H_ + h) * NCHUNK];
#pragma unroll
  for (int j = 0; j < NCHUNK / 4; ++j) {
    float4v p = Pv[j], s = Sv[j], cc;
    cc[0] = cur; cur = p[0] * cur + s[0];
    cc[1] = cur; cur = p[1] * cur + s[1];
    cc[2] = cur; cur = p[2] * cur + s[2];
    cc[3] = cur; cur = p[3] * cur + s[3];
    Cv[j] = cc;
  }
}

// ------------- scan pass 3: replay chunks with carries, write out (4 h per thread) -------------
__global__ __launch_bounds__(256) void scan_pass3(const halfx8* __restrict__ aw,
                                                  const float* __restrict__ carry,
                                                  float* __restrict__ out) {
  int c = blockIdx.x;
  int b = blockIdx.y;
  int h4 = threadIdx.x;   // h = h4*4
  size_t base = (size_t)(b * T_ + c * CLEN) * (H_ / 4) + h4;
  size_t cb = ((size_t)b * H_ + h4 * 4) * NCHUNK + c;
  float c0 = carry[cb], c1 = carry[cb + NCHUNK], c2 = carry[cb + 2 * NCHUNK], c3 = carry[cb + 3 * NCHUNK];
  size_t obase = ((size_t)b * (T_ + 1) + c * CLEN + 1) * (H_ / 4) + h4;
  float4v* outv = (float4v*)out;
#pragma unroll 8
  for (int i = 0; i < CLEN; ++i) {
    halfx8 v = aw[base + (size_t)i * (H_ / 4)];
    c0 = (float)v[0] * c0 + (float)v[1];
    c1 = (float)v[2] * c1 + (float)v[3];
    c2 = (float)v[4] * c2 + (float)v[5];
    c3 = (float)v[6] * c3 + (float)v[7];
    float4v o = { c0, c1, c2, c3 };
    outv[obase + (size_t)i * (H_ / 4)] = o;
  }
}

extern "C" void kernel_launch(void* const* d_in, const int* in_sizes, int n_in,
                              void* d_out, int out_size, void* d_ws, size_t ws_size,
                              hipStream_t stream) {
  const float* x  = (const float*)d_in[0];
  const float* h0 = (const float*)d_in[1];
  const float* Wz = (const float*)d_in[2];
  const float* bz = (const float*)d_in[3];
  const float* Wh = (const float*)d_in[4];
  const float* bh = (const float*)d_in[5];
  float* out = (float*)d_out;

  char* ws = (char*)d_ws;
  // layout: xb 64MB | wzt 2MB | wht 2MB | aw 128MB | P 2MB | S 2MB | carry 2MB
  unsigned short* xb  = (unsigned short*)(ws);
  unsigned short* wzt = (unsigned short*)(ws + 67108864ULL);
  unsigned short* wht = (unsigned short*)(ws + 69206016ULL);
  aw2_t* aw_ws = (aw2_t*)(ws + 71303168ULL);
  float* P_ws  = (float*)(ws + 71303168ULL + 134217728ULL);
  float* S_ws  = (float*)(ws + 71303168ULL + 134217728ULL + 2097152ULL);
  float* c_ws  = (float*)(ws + 71303168ULL + 134217728ULL + 2ULL * 2097152ULL);

  hipLaunchKernelGGL(cast_x_kernel, dim3(16384), dim3(256), 0, stream, x, xb);
  hipLaunchKernelGGL(transpose_w_kernel, dim3(32, 32, 2), dim3(32, 8), 0, stream, Wz, Wh, wzt, wht);
  hipLaunchKernelGGL(gemm_kernel, dim3(4096), dim3(256), 0, stream,
                     xb, wzt, wht, bz, bh, aw_ws);
  hipLaunchKernelGGL(scan_pass1, dim3(NCHUNK, B_), dim3(256), 0, stream,
                     (const halfx8*)aw_ws, P_ws, S_ws);
  hipLaunchKernelGGL(scan_pass2, dim3(32), dim3(256), 0, stream, h0, P_ws, S_ws, c_ws, out);
  hipLaunchKernelGGL(scan_pass3, dim3(NCHUNK, B_), dim3(256), 0, stream,
                     (const halfx8*)aw_ws, c_ws, out);
}

// Round 4
// 493.477 us; speedup vs baseline: 1.2582x; 1.2582x over previous
//
#include <hip/hip_runtime.h>
#include <hip/hip_bf16.h>
#include <cstdint>
#include <cstddef>

#define B_ 8
#define T_ 4096
#define D_ 1024
#define H_ 1024
#define M_ (B_*T_)
#define NCHUNK 64
#define CLEN 64

using bf16x8   = __attribute__((ext_vector_type(8))) __bf16;
using floatx4  = __attribute__((ext_vector_type(4))) float;
using float4v  = __attribute__((ext_vector_type(4))) float;
using ushort4v = __attribute__((ext_vector_type(4))) unsigned short;
using aw2_t    = __attribute__((ext_vector_type(2))) _Float16;  // packed (a, w)
using halfx8   = __attribute__((ext_vector_type(8))) _Float16;  // 4 aw2 pairs

__device__ inline unsigned short f2bf(float f) {
  union { float f; unsigned u; } v; v.f = f;
  unsigned u = v.u;
  u += 0x7fffu + ((u >> 16) & 1u);   // round-to-nearest-even
  return (unsigned short)(u >> 16);
}

__device__ inline void async_load16(const void* g, void* l) {
  __builtin_amdgcn_global_load_lds((const __attribute__((address_space(1))) void*)g,
                                   (__attribute__((address_space(3))) void*)l,
                                   16, 0, 0);
}

// ---------------- cast x (fp32 -> bf16), 8 elems/thread ----------------
__global__ __launch_bounds__(256) void cast_x_kernel(const float* __restrict__ x,
                                                     unsigned short* __restrict__ xb) {
  size_t i = ((size_t)blockIdx.x * 256 + threadIdx.x) * 2;  // 2 groups of 4
#pragma unroll
  for (int j = 0; j < 2; ++j) {
    float4v v = ((const float4v*)x)[i + j];
    ushort4v o = { f2bf(v[0]), f2bf(v[1]), f2bf(v[2]), f2bf(v[3]) };
    ((ushort4v*)xb)[i + j] = o;
  }
}

// ------------- transpose + cast W [K][N] -> Wt [N][K] bf16 -------------
__global__ __launch_bounds__(256) void transpose_w_kernel(const float* __restrict__ Wz,
                                                          const float* __restrict__ Wh,
                                                          unsigned short* __restrict__ Wzt,
                                                          unsigned short* __restrict__ Wht) {
  __shared__ float tile[32][33];
  const float* W = blockIdx.z ? Wh : Wz;
  unsigned short* Wt = blockIdx.z ? Wht : Wzt;
  int n0 = blockIdx.x * 32, k0 = blockIdx.y * 32;
#pragma unroll
  for (int j = 0; j < 4; ++j) {
    int kr = threadIdx.y + j * 8;
    tile[kr][threadIdx.x] = W[(size_t)(k0 + kr) * H_ + n0 + threadIdx.x];
  }
  __syncthreads();
#pragma unroll
  for (int j = 0; j < 4; ++j) {
    int nr = threadIdx.y + j * 8;
    Wt[(size_t)(n0 + nr) * D_ + k0 + threadIdx.x] = f2bf(tile[threadIdx.x][nr]);
  }
}

// ------------- dual-output MFMA GEMM + activation epilogue -------------
// 128x128 dual tile (m97 shape): BK=32, A+Bz+Bh staged in LDS (24 KB),
// 4 waves 2x2, each wave 64x64 per output: 32 MFMA + 12 ds_read_b128 /k-step.
// XCD swizzle: 8 n-tiles of one m-strip consecutive on one XCD.
__global__ __launch_bounds__(256, 2) void gemm_kernel(
    const unsigned short* __restrict__ xb,    // [M_][D_] bf16
    const unsigned short* __restrict__ wzt,   // [H_][D_] bf16 (transposed)
    const unsigned short* __restrict__ wht,   // [H_][D_] bf16
    const float* __restrict__ bz, const float* __restrict__ bh,
    aw2_t* __restrict__ aw_out) {
  __shared__ __align__(16) unsigned short ldsA[128 * 32];
  __shared__ __align__(16) unsigned short ldsBz[128 * 32];
  __shared__ __align__(16) unsigned short ldsBh[128 * 32];

  const int tid = threadIdx.x;
  const int lane = tid & 63, wid = tid >> 6;
  const int wm = wid >> 1, wn = wid & 1;
  const int row16 = lane & 15, quad = lane >> 4;

  // XCD-aware swizzle: dispatch assigns block g to XCD g%8.
  int g = blockIdx.x;
  int x = g & 7, j = g >> 3;           // j in 0..255
  int n_idx = j & 7;                   // 8 n-tiles per m-strip, same XCD
  int m_idx = (x << 5) | (j >> 3);     // 32 m-strips per XCD
  const int m0 = m_idx * 128, n0 = n_idx * 128;

  floatx4 accz[4][4], acch[4][4];
#pragma unroll
  for (int mi = 0; mi < 4; ++mi)
#pragma unroll
    for (int ni = 0; ni < 4; ++ni) {
      accz[mi][ni] = (floatx4){0.f, 0.f, 0.f, 0.f};
      acch[mi][ni] = (floatx4){0.f, 0.f, 0.f, 0.f};
    }

  // staging addresses: seg s (0..511): row = s>>2, 16B col = s&3
  const unsigned short* a0 = xb  + (size_t)(m0 + (tid >> 2)) * D_ + (tid & 3) * 8;
  const unsigned short* a1 = xb  + (size_t)(m0 + 64 + (tid >> 2)) * D_ + (tid & 3) * 8;
  const unsigned short* z0 = wzt + (size_t)(n0 + (tid >> 2)) * D_ + (tid & 3) * 8;
  const unsigned short* z1 = wzt + (size_t)(n0 + 64 + (tid >> 2)) * D_ + (tid & 3) * 8;
  const unsigned short* h0p = wht + (size_t)(n0 + (tid >> 2)) * D_ + (tid & 3) * 8;
  const unsigned short* h1p = wht + (size_t)(n0 + 64 + (tid >> 2)) * D_ + (tid & 3) * 8;

  for (int kk = 0; kk < D_; kk += 32) {
    async_load16(a0 + kk, &ldsA[tid * 8]);
    async_load16(a1 + kk, &ldsA[(tid + 256) * 8]);
    async_load16(z0 + kk, &ldsBz[tid * 8]);
    async_load16(z1 + kk, &ldsBz[(tid + 256) * 8]);
    async_load16(h0p + kk, &ldsBh[tid * 8]);
    async_load16(h1p + kk, &ldsBh[(tid + 256) * 8]);
    __syncthreads();

    bf16x8 af[4], bzf[4], bhf[4];
#pragma unroll
    for (int mi = 0; mi < 4; ++mi)
      af[mi] = *(const bf16x8*)&ldsA[(wm * 64 + mi * 16 + row16) * 32 + quad * 8];
#pragma unroll
    for (int ni = 0; ni < 4; ++ni) {
      bzf[ni] = *(const bf16x8*)&ldsBz[(wn * 64 + ni * 16 + row16) * 32 + quad * 8];
      bhf[ni] = *(const bf16x8*)&ldsBh[(wn * 64 + ni * 16 + row16) * 32 + quad * 8];
    }
#pragma unroll
    for (int mi = 0; mi < 4; ++mi)
#pragma unroll
      for (int ni = 0; ni < 4; ++ni) {
        accz[mi][ni] = __builtin_amdgcn_mfma_f32_16x16x32_bf16(af[mi], bzf[ni], accz[mi][ni], 0, 0, 0);
        acch[mi][ni] = __builtin_amdgcn_mfma_f32_16x16x32_bf16(af[mi], bhf[ni], acch[mi][ni], 0, 0, 0);
      }
    __syncthreads();
  }

  // epilogue: C/D layout col=lane&15, row=quad*4+reg
#pragma unroll
  for (int mi = 0; mi < 4; ++mi) {
#pragma unroll
    for (int ni = 0; ni < 4; ++ni) {
      int col = n0 + wn * 64 + ni * 16 + row16;
      float bzv = bz[col], bhv = bh[col];
#pragma unroll
      for (int r = 0; r < 4; ++r) {
        int row = m0 + wm * 64 + mi * 16 + quad * 4 + r;
        float k   = accz[mi][ni][r] + bzv;
        float pre = acch[mi][ni][r] + bhv;
        float z  = 1.f / (1.f + __expf(-k));   // sigmoid(k)
        float av = 1.f / (1.f + __expf(k));    // sigmoid(-k) = 1-z
        float gg = (pre >= 0.f) ? (pre + 0.5f) : 1.f / (1.f + __expf(-pre));
        aw2_t o = { (_Float16)av, (_Float16)(z * gg) };
        aw_out[(size_t)row * H_ + col] = o;
      }
    }
  }
}

// ------------- scan pass 1: per-chunk (P = prod a, S = local scan), 4 h per thread -------------
// P,S layout: [b][h][c]  (contiguous in c for fast pass2)
__global__ __launch_bounds__(256) void scan_pass1(const halfx8* __restrict__ aw,
                                                  float* __restrict__ P, float* __restrict__ S) {
  int c = blockIdx.x;     // chunk
  int b = blockIdx.y;     // batch
  int h4 = threadIdx.x;   // h = h4*4
  size_t base = (size_t)(b * T_ + c * CLEN) * (H_ / 4) + h4;
  float p0 = 1.f, p1 = 1.f, p2 = 1.f, p3 = 1.f;
  float s0 = 0.f, s1 = 0.f, s2 = 0.f, s3 = 0.f;
#pragma unroll 8
  for (int i = 0; i < CLEN; ++i) {
    halfx8 v = aw[base + (size_t)i * (H_ / 4)];
    float a0 = (float)v[0], w0 = (float)v[1];
    float a1 = (float)v[2], w1 = (float)v[3];
    float a2 = (float)v[4], w2 = (float)v[5];
    float a3 = (float)v[6], w3 = (float)v[7];
    s0 = a0 * s0 + w0; p0 *= a0;
    s1 = a1 * s1 + w1; p1 *= a1;
    s2 = a2 * s2 + w2; p2 *= a2;
    s3 = a3 * s3 + w3; p3 *= a3;
  }
  size_t o = ((size_t)b * H_ + h4 * 4) * NCHUNK + c;
  P[o] = p0; P[o + NCHUNK] = p1; P[o + 2 * NCHUNK] = p2; P[o + 3 * NCHUNK] = p3;
  S[o] = s0; S[o + NCHUNK] = s1; S[o + 2 * NCHUNK] = s2; S[o + 3 * NCHUNK] = s3;
}

// ------------- scan pass 2: chunk-level carries + out[:,0,:] -------------
__global__ __launch_bounds__(256) void scan_pass2(const float* __restrict__ h0,
                                                  const float* __restrict__ P,
                                                  const float* __restrict__ S,
                                                  float* __restrict__ carry,
                                                  float* __restrict__ out) {
  int gid = blockIdx.x * 256 + threadIdx.x;  // 0..8191
  int b = gid >> 10, h = gid & 1023;
  float v = h0[(size_t)b * H_ + h];
  float cur = (v >= 0.f) ? (v + 0.5f) : 1.f / (1.f + __expf(-v));  // g(h0)
  out[((size_t)b * (T_ + 1)) * H_ + h] = cur;
  const float4v* Pv = (const float4v*)&P[((size_t)b * H_ + h) * NCHUNK];
  const float4v* Sv = (const float4v*)&S[((size_t)b * H_ + h) * NCHUNK];
  float4v* Cv = (float4v*)&carry[((size_t)b * H_ + h) * NCHUNK];
#pragma unroll
  for (int j = 0; j < NCHUNK / 4; ++j) {
    float4v p = Pv[j], s = Sv[j], cc;
    cc[0] = cur; cur = p[0] * cur + s[0];
    cc[1] = cur; cur = p[1] * cur + s[1];
    cc[2] = cur; cur = p[2] * cur + s[2];
    cc[3] = cur; cur = p[3] * cur + s[3];
    Cv[j] = cc;
  }
}

// ------------- scan pass 3: replay chunks with carries, write out (4 h per thread) -------------
__global__ __launch_bounds__(256) void scan_pass3(const halfx8* __restrict__ aw,
                                                  const float* __restrict__ carry,
                                                  float* __restrict__ out) {
  int c = blockIdx.x;
  int b = blockIdx.y;
  int h4 = threadIdx.x;   // h = h4*4
  size_t base = (size_t)(b * T_ + c * CLEN) * (H_ / 4) + h4;
  size_t cb = ((size_t)b * H_ + h4 * 4) * NCHUNK + c;
  float c0 = carry[cb], c1 = carry[cb + NCHUNK], c2 = carry[cb + 2 * NCHUNK], c3 = carry[cb + 3 * NCHUNK];
  size_t obase = ((size_t)b * (T_ + 1) + c * CLEN + 1) * (H_ / 4) + h4;
  float4v* outv = (float4v*)out;
#pragma unroll 8
  for (int i = 0; i < CLEN; ++i) {
    halfx8 v = aw[base + (size_t)i * (H_ / 4)];
    c0 = (float)v[0] * c0 + (float)v[1];
    c1 = (float)v[2] * c1 + (float)v[3];
    c2 = (float)v[4] * c2 + (float)v[5];
    c3 = (float)v[6] * c3 + (float)v[7];
    float4v o = { c0, c1, c2, c3 };
    outv[obase + (size_t)i * (H_ / 4)] = o;
  }
}

extern "C" void kernel_launch(void* const* d_in, const int* in_sizes, int n_in,
                              void* d_out, int out_size, void* d_ws, size_t ws_size,
                              hipStream_t stream) {
  const float* x  = (const float*)d_in[0];
  const float* h0 = (const float*)d_in[1];
  const float* Wz = (const float*)d_in[2];
  const float* bz = (const float*)d_in[3];
  const float* Wh = (const float*)d_in[4];
  const float* bh = (const float*)d_in[5];
  float* out = (float*)d_out;

  char* ws = (char*)d_ws;
  // layout: xb 64MB | wzt 2MB | wht 2MB | aw 128MB | P 2MB | S 2MB | carry 2MB
  unsigned short* xb  = (unsigned short*)(ws);
  unsigned short* wzt = (unsigned short*)(ws + 67108864ULL);
  unsigned short* wht = (unsigned short*)(ws + 69206016ULL);
  aw2_t* aw_ws = (aw2_t*)(ws + 71303168ULL);
  float* P_ws  = (float*)(ws + 71303168ULL + 134217728ULL);
  float* S_ws  = (float*)(ws + 71303168ULL + 134217728ULL + 2097152ULL);
  float* c_ws  = (float*)(ws + 71303168ULL + 134217728ULL + 2ULL * 2097152ULL);

  hipLaunchKernelGGL(cast_x_kernel, dim3(16384), dim3(256), 0, stream, x, xb);
  hipLaunchKernelGGL(transpose_w_kernel, dim3(32, 32, 2), dim3(32, 8), 0, stream, Wz, Wh, wzt, wht);
  hipLaunchKernelGGL(gemm_kernel, dim3(2048), dim3(256), 0, stream,
                     xb, wzt, wht, bz, bh, aw_ws);
  hipLaunchKernelGGL(scan_pass1, dim3(NCHUNK, B_), dim3(256), 0, stream,
                     (const halfx8*)aw_ws, P_ws, S_ws);
  hipLaunchKernelGGL(scan_pass2, dim3(32), dim3(256), 0, stream, h0, P_ws, S_ws, c_ws, out);
  hipLaunchKernelGGL(scan_pass3, dim3(NCHUNK, B_), dim3(256), 0, stream,
                     (const halfx8*)aw_ws, c_ws, out);
}

// Round 5
// 472.771 us; speedup vs baseline: 1.3133x; 1.0438x over previous
//
#include <hip/hip_runtime.h>
#include <hip/hip_bf16.h>
#include <cstdint>
#include <cstddef>

#define B_ 8
#define T_ 4096
#define D_ 1024
#define H_ 1024
#define M_ (B_*T_)
#define NCHUNK 64
#define CLEN 64

using bf16x8   = __attribute__((ext_vector_type(8))) __bf16;
using floatx4  = __attribute__((ext_vector_type(4))) float;
using float4v  = __attribute__((ext_vector_type(4))) float;
using ushort4v = __attribute__((ext_vector_type(4))) unsigned short;
using aw2_t    = __attribute__((ext_vector_type(2))) _Float16;  // packed (a, w)
using halfx8   = __attribute__((ext_vector_type(8))) _Float16;  // 4 aw2 pairs

__device__ inline unsigned short f2bf(float f) {
  union { float f; unsigned u; } v; v.f = f;
  unsigned u = v.u;
  u += 0x7fffu + ((u >> 16) & 1u);   // round-to-nearest-even
  return (unsigned short)(u >> 16);
}

__device__ inline void async_load16(const void* g, void* l) {
  __builtin_amdgcn_global_load_lds((const __attribute__((address_space(1))) void*)g,
                                   (__attribute__((address_space(3))) void*)l,
                                   16, 0, 0);
}

// ---------------- cast x (fp32 -> bf16), 8 elems/thread ----------------
__global__ __launch_bounds__(256) void cast_x_kernel(const float* __restrict__ x,
                                                     unsigned short* __restrict__ xb) {
  size_t i = ((size_t)blockIdx.x * 256 + threadIdx.x) * 2;  // 2 groups of 4
#pragma unroll
  for (int j = 0; j < 2; ++j) {
    float4v v = ((const float4v*)x)[i + j];
    ushort4v o = { f2bf(v[0]), f2bf(v[1]), f2bf(v[2]), f2bf(v[3]) };
    ((ushort4v*)xb)[i + j] = o;
  }
}

// ------------- transpose + cast W [K][N] -> Wt [N][K] bf16 -------------
__global__ __launch_bounds__(256) void transpose_w_kernel(const float* __restrict__ Wz,
                                                          const float* __restrict__ Wh,
                                                          unsigned short* __restrict__ Wzt,
                                                          unsigned short* __restrict__ Wht) {
  __shared__ float tile[32][33];
  const float* W = blockIdx.z ? Wh : Wz;
  unsigned short* Wt = blockIdx.z ? Wht : Wzt;
  int n0 = blockIdx.x * 32, k0 = blockIdx.y * 32;
#pragma unroll
  for (int j = 0; j < 4; ++j) {
    int kr = threadIdx.y + j * 8;
    tile[kr][threadIdx.x] = W[(size_t)(k0 + kr) * H_ + n0 + threadIdx.x];
  }
  __syncthreads();
#pragma unroll
  for (int j = 0; j < 4; ++j) {
    int nr = threadIdx.y + j * 8;
    Wt[(size_t)(n0 + nr) * D_ + k0 + threadIdx.x] = f2bf(tile[threadIdx.x][nr]);
  }
}

// ------------- dual-output MFMA GEMM + activation epilogue -------------
// 128x128 dual tile, BK=64 (16 k-iters, half the barrier drains of BK=32),
// XOR-swizzled LDS: row r's 16B k-block j stored at slot (j+r)&7 -> frag
// reads spread over 8 banks (2-way, free). Global source absorbs the
// swizzle; LDS destinations remain lane-contiguous for global_load_lds.
// 4 waves 2x2, each 64x64 per output; 64 MFMA + 24 ds_read_b128 per iter.
__global__ __launch_bounds__(256, 2) void gemm_kernel(
    const unsigned short* __restrict__ xb,    // [M_][D_] bf16
    const unsigned short* __restrict__ wzt,   // [H_][D_] bf16 (transposed)
    const unsigned short* __restrict__ wht,   // [H_][D_] bf16
    const float* __restrict__ bz, const float* __restrict__ bh,
    aw2_t* __restrict__ aw_out) {
  __shared__ __align__(16) unsigned short ldsA[128 * 64];
  __shared__ __align__(16) unsigned short ldsBz[128 * 64];
  __shared__ __align__(16) unsigned short ldsBh[128 * 64];

  const int tid = threadIdx.x;
  const int lane = tid & 63, wid = tid >> 6;
  const int wm = wid >> 1, wn = wid & 1;
  const int row16 = lane & 15, quad = lane >> 4;

  // XCD-aware swizzle: 8 n-tiles of one m-strip consecutive on one XCD.
  int g = blockIdx.x;
  int x = g & 7, j = g >> 3;           // j in 0..255
  int n_idx = j & 7;
  int m_idx = (x << 5) | (j >> 3);
  const int m0 = m_idx * 128, n0 = n_idx * 128;

  floatx4 accz[4][4], acch[4][4];
#pragma unroll
  for (int mi = 0; mi < 4; ++mi)
#pragma unroll
    for (int ni = 0; ni < 4; ++ni) {
      accz[mi][ni] = (floatx4){0.f, 0.f, 0.f, 0.f};
      acch[mi][ni] = (floatx4){0.f, 0.f, 0.f, 0.f};
    }

  // staging: seg s = tid + 256*t (t=0..3): row = s>>3 = (tid>>3)+32t,
  // stored slot p = s&7 = tid&7, logical k-block j = (p - row)&7 =
  // ((tid&7) - (tid>>3))&7  (32t == 0 mod 8) -> t-independent.
  const int srow = tid >> 3;
  const int jblk = ((tid & 7) - srow) & 7;
  const unsigned short* aSrc  = xb  + (size_t)(m0 + srow) * D_ + jblk * 8;
  const unsigned short* zSrc  = wzt + (size_t)(n0 + srow) * D_ + jblk * 8;
  const unsigned short* hSrc  = wht + (size_t)(n0 + srow) * D_ + jblk * 8;

  // frag-read slot: p(kh) = (kh*4 + quad + row16) & 7  (row%8 == row16%8)
  const int p0 = (quad + row16) & 7;
  const int p1 = p0 ^ 4;

  for (int kk = 0; kk < D_; kk += 64) {
#pragma unroll
    for (int t = 0; t < 4; ++t) {
      size_t roff = (size_t)(32 * t) * D_ + kk;
      int doff = (tid + 256 * t) * 8;
      async_load16(aSrc + roff, &ldsA[doff]);
      async_load16(zSrc + roff, &ldsBz[doff]);
      async_load16(hSrc + roff, &ldsBh[doff]);
    }
    __syncthreads();

#pragma unroll
    for (int kh = 0; kh < 2; ++kh) {
      const int p = kh ? p1 : p0;
      bf16x8 af[4], bzf[4], bhf[4];
#pragma unroll
      for (int mi = 0; mi < 4; ++mi)
        af[mi] = *(const bf16x8*)&ldsA[(wm * 64 + mi * 16 + row16) * 64 + p * 8];
#pragma unroll
      for (int ni = 0; ni < 4; ++ni) {
        bzf[ni] = *(const bf16x8*)&ldsBz[(wn * 64 + ni * 16 + row16) * 64 + p * 8];
        bhf[ni] = *(const bf16x8*)&ldsBh[(wn * 64 + ni * 16 + row16) * 64 + p * 8];
      }
#pragma unroll
      for (int mi = 0; mi < 4; ++mi)
#pragma unroll
        for (int ni = 0; ni < 4; ++ni) {
          accz[mi][ni] = __builtin_amdgcn_mfma_f32_16x16x32_bf16(af[mi], bzf[ni], accz[mi][ni], 0, 0, 0);
          acch[mi][ni] = __builtin_amdgcn_mfma_f32_16x16x32_bf16(af[mi], bhf[ni], acch[mi][ni], 0, 0, 0);
        }
    }
    __syncthreads();
  }

  // epilogue: C/D layout col=lane&15, row=quad*4+reg
#pragma unroll
  for (int mi = 0; mi < 4; ++mi) {
#pragma unroll
    for (int ni = 0; ni < 4; ++ni) {
      int col = n0 + wn * 64 + ni * 16 + row16;
      float bzv = bz[col], bhv = bh[col];
#pragma unroll
      for (int r = 0; r < 4; ++r) {
        int row = m0 + wm * 64 + mi * 16 + quad * 4 + r;
        float k   = accz[mi][ni][r] + bzv;
        float pre = acch[mi][ni][r] + bhv;
        float z  = 1.f / (1.f + __expf(-k));   // sigmoid(k)
        float av = 1.f / (1.f + __expf(k));    // sigmoid(-k) = 1-z
        float gg = (pre >= 0.f) ? (pre + 0.5f) : 1.f / (1.f + __expf(-pre));
        aw2_t o = { (_Float16)av, (_Float16)(z * gg) };
        aw_out[(size_t)row * H_ + col] = o;
      }
    }
  }
}

// ------------- scan pass 1: per-chunk (P = prod a, S = local scan), 4 h per thread -------------
// P,S layout: [b][h][c]  (contiguous in c for fast pass2)
__global__ __launch_bounds__(256) void scan_pass1(const halfx8* __restrict__ aw,
                                                  float* __restrict__ P, float* __restrict__ S) {
  int c = blockIdx.x;     // chunk
  int b = blockIdx.y;     // batch
  int h4 = threadIdx.x;   // h = h4*4
  size_t base = (size_t)(b * T_ + c * CLEN) * (H_ / 4) + h4;
  float p0 = 1.f, p1 = 1.f, p2 = 1.f, p3 = 1.f;
  float s0 = 0.f, s1 = 0.f, s2 = 0.f, s3 = 0.f;
#pragma unroll 8
  for (int i = 0; i < CLEN; ++i) {
    halfx8 v = aw[base + (size_t)i * (H_ / 4)];
    float a0 = (float)v[0], w0 = (float)v[1];
    float a1 = (float)v[2], w1 = (float)v[3];
    float a2 = (float)v[4], w2 = (float)v[5];
    float a3 = (float)v[6], w3 = (float)v[7];
    s0 = a0 * s0 + w0; p0 *= a0;
    s1 = a1 * s1 + w1; p1 *= a1;
    s2 = a2 * s2 + w2; p2 *= a2;
    s3 = a3 * s3 + w3; p3 *= a3;
  }
  size_t o = ((size_t)b * H_ + h4 * 4) * NCHUNK + c;
  P[o] = p0; P[o + NCHUNK] = p1; P[o + 2 * NCHUNK] = p2; P[o + 3 * NCHUNK] = p3;
  S[o] = s0; S[o + NCHUNK] = s1; S[o + 2 * NCHUNK] = s2; S[o + 3 * NCHUNK] = s3;
}

// ------------- scan pass 2: chunk-level carries + out[:,0,:] -------------
__global__ __launch_bounds__(256) void scan_pass2(const float* __restrict__ h0,
                                                  const float* __restrict__ P,
                                                  const float* __restrict__ S,
                                                  float* __restrict__ carry,
                                                  float* __restrict__ out) {
  int gid = blockIdx.x * 256 + threadIdx.x;  // 0..8191
  int b = gid >> 10, h = gid & 1023;
  float v = h0[(size_t)b * H_ + h];
  float cur = (v >= 0.f) ? (v + 0.5f) : 1.f / (1.f + __expf(-v));  // g(h0)
  out[((size_t)b * (T_ + 1)) * H_ + h] = cur;
  const float4v* Pv = (const float4v*)&P[((size_t)b * H_ + h) * NCHUNK];
  const float4v* Sv = (const float4v*)&S[((size_t)b * H_ + h) * NCHUNK];
  float4v* Cv = (float4v*)&carry[((size_t)b * H_ + h) * NCHUNK];
#pragma unroll
  for (int j = 0; j < NCHUNK / 4; ++j) {
    float4v p = Pv[j], s = Sv[j], cc;
    cc[0] = cur; cur = p[0] * cur + s[0];
    cc[1] = cur; cur = p[1] * cur + s[1];
    cc[2] = cur; cur = p[2] * cur + s[2];
    cc[3] = cur; cur = p[3] * cur + s[3];
    Cv[j] = cc;
  }
}

// ------------- scan pass 3: replay chunks with carries, write out (4 h per thread) -------------
__global__ __launch_bounds__(256) void scan_pass3(const halfx8* __restrict__ aw,
                                                  const float* __restrict__ carry,
                                                  float* __restrict__ out) {
  int c = blockIdx.x;
  int b = blockIdx.y;
  int h4 = threadIdx.x;   // h = h4*4
  size_t base = (size_t)(b * T_ + c * CLEN) * (H_ / 4) + h4;
  size_t cb = ((size_t)b * H_ + h4 * 4) * NCHUNK + c;
  float c0 = carry[cb], c1 = carry[cb + NCHUNK], c2 = carry[cb + 2 * NCHUNK], c3 = carry[cb + 3 * NCHUNK];
  size_t obase = ((size_t)b * (T_ + 1) + c * CLEN + 1) * (H_ / 4) + h4;
  float4v* outv = (float4v*)out;
#pragma unroll 8
  for (int i = 0; i < CLEN; ++i) {
    halfx8 v = aw[base + (size_t)i * (H_ / 4)];
    c0 = (float)v[0] * c0 + (float)v[1];
    c1 = (float)v[2] * c1 + (float)v[3];
    c2 = (float)v[4] * c2 + (float)v[5];
    c3 = (float)v[6] * c3 + (float)v[7];
    float4v o = { c0, c1, c2, c3 };
    outv[obase + (size_t)i * (H_ / 4)] = o;
  }
}

extern "C" void kernel_launch(void* const* d_in, const int* in_sizes, int n_in,
                              void* d_out, int out_size, void* d_ws, size_t ws_size,
                              hipStream_t stream) {
  const float* x  = (const float*)d_in[0];
  const float* h0 = (const float*)d_in[1];
  const float* Wz = (const float*)d_in[2];
  const float* bz = (const float*)d_in[3];
  const float* Wh = (const float*)d_in[4];
  const float* bh = (const float*)d_in[5];
  float* out = (float*)d_out;

  char* ws = (char*)d_ws;
  // layout: xb 64MB | wzt 2MB | wht 2MB | aw 128MB | P 2MB | S 2MB | carry 2MB
  unsigned short* xb  = (unsigned short*)(ws);
  unsigned short* wzt = (unsigned short*)(ws + 67108864ULL);
  unsigned short* wht = (unsigned short*)(ws + 69206016ULL);
  aw2_t* aw_ws = (aw2_t*)(ws + 71303168ULL);
  float* P_ws  = (float*)(ws + 71303168ULL + 134217728ULL);
  float* S_ws  = (float*)(ws + 71303168ULL + 134217728ULL + 2097152ULL);
  float* c_ws  = (float*)(ws + 71303168ULL + 134217728ULL + 2ULL * 2097152ULL);

  hipLaunchKernelGGL(cast_x_kernel, dim3(16384), dim3(256), 0, stream, x, xb);
  hipLaunchKernelGGL(transpose_w_kernel, dim3(32, 32, 2), dim3(32, 8), 0, stream, Wz, Wh, wzt, wht);
  hipLaunchKernelGGL(gemm_kernel, dim3(2048), dim3(256), 0, stream,
                     xb, wzt, wht, bz, bh, aw_ws);
  hipLaunchKernelGGL(scan_pass1, dim3(NCHUNK, B_), dim3(256), 0, stream,
                     (const halfx8*)aw_ws, P_ws, S_ws);
  hipLaunchKernelGGL(scan_pass2, dim3(32), dim3(256), 0, stream, h0, P_ws, S_ws, c_ws, out);
  hipLaunchKernelGGL(scan_pass3, dim3(NCHUNK, B_), dim3(256), 0, stream,
                     (const halfx8*)aw_ws, c_ws, out);
}